// Round 5
// baseline (183.256 us; speedup 1.0000x reference)
//
#include <hip/hip_runtime.h>
#include <hip/hip_bf16.h>

#define NN 4096
#define IN_F 512
#define HALF 256
#define FF 64
#define ALPHA 0.2f
#define EPSV 1e-5f
#define CAP1 256
#define CAP2 1024
#define WHB (NN / 8)   // wh blocks, 8 rows each

typedef unsigned long long u64;
typedef unsigned int u32;

__device__ __forceinline__ float lrelu(float x){ return x > 0.f ? x : ALPHA * x; }

__device__ __forceinline__ float wave_fmax(float v){
    #pragma unroll
    for (int off = 32; off; off >>= 1) v = fmaxf(v, __shfl_xor(v, off, 64));
    return v;
}
__device__ __forceinline__ float wave_fsum(float v){
    #pragma unroll
    for (int off = 32; off; off >>= 1) v += __shfl_xor(v, off, 64);
    return v;
}

// Wave-wide compaction of set bits (one u64 word per lane) into an index list.
__device__ __forceinline__ int build_idx(u64 bits, int lane, int cap, int* __restrict__ nbr){
    int pc = __popcll(bits);
    int scan = pc;
    #pragma unroll
    for (int off = 1; off < 64; off <<= 1) {
        int v = __shfl_up(scan, off, 64);
        if (lane >= off) scan += v;
    }
    int total = __shfl(scan, 63, 64);
    int pos = scan - pc;
    while (bits) {
        int b = __builtin_ctzll(bits);
        bits &= bits - 1;
        if (pos < cap) nbr[pos] = (lane << 6) | b;
        ++pos;
    }
    return total;
}

// ---------------- Kernel 1: fused pack (blocks < NN) + Wh GEMV (blocks >= NN) ----------------
// pack is HBM-BW-bound, wh is L2/VALU-bound -> co-scheduling overlaps them.
__global__ __launch_bounds__(256) void packwh_kernel(const float* __restrict__ adj,
                                                     u64* __restrict__ packA,
                                                     const float* __restrict__ h,
                                                     const float* __restrict__ W1,
                                                     const float* __restrict__ W2,
                                                     const float* __restrict__ a,
                                                     float* __restrict__ Wh1,
                                                     float* __restrict__ Wh2,
                                                     float* __restrict__ s11,
                                                     float* __restrict__ s12,
                                                     float* __restrict__ s21,
                                                     float* __restrict__ s22) {
    __shared__ float hs[8 * IN_F];   // 16 KB (used by wh branch only)
    int tid = threadIdx.x;
    if (blockIdx.x < NN) {
        // ---- pack: one adjacency row -> 64 u64 words ----
        int i = blockIdx.x;
        int wave = tid >> 6, lane = tid & 63;
        const float* row = adj + (size_t)i * NN;
        #pragma unroll
        for (int t = 0; t < NN / 256; ++t) {
            int col = t * 256 + tid;
            u64 m = __ballot(row[col] > 0.f);
            if (lane == 0) packA[(size_t)i * 64 + t * 4 + wave] = m;
        }
    } else {
        // ---- wh: 8 rows per block; waves 0-1 -> W1, waves 2-3 -> W2 ----
        int r0 = (blockIdx.x - NN) * 8;
        const float4* hsrc = (const float4*)(h + (size_t)r0 * IN_F);
        float4* hdst = (float4*)hs;
        #pragma unroll
        for (int t = 0; t < 4; ++t) hdst[tid + 256 * t] = hsrc[tid + 256 * t];
        __syncthreads();

        int w = tid >> 6, f = tid & 63;
        int br2 = w >> 1;                 // 0: branch1, 1: branch2
        int rbase = (w & 1) * 4;          // rows rbase..rbase+3 of the 8
        const float* W = br2 ? W2 : W1;
        const float* hw = hs + rbase * IN_F + br2 * HALF;
        float acc0 = 0.f, acc1 = 0.f, acc2 = 0.f, acc3 = 0.f;
        #pragma unroll 4
        for (int k = 0; k < HALF; ++k) {
            float wt = W[k * FF + f];
            acc0 += hw[k] * wt;
            acc1 += hw[IN_F + k] * wt;
            acc2 += hw[2 * IN_F + k] * wt;
            acc3 += hw[3 * IN_F + k] * wt;
        }
        float* Wh = br2 ? Wh2 : Wh1;
        int rr = r0 + rbase;
        Wh[(size_t)(rr + 0) * FF + f] = acc0;
        Wh[(size_t)(rr + 1) * FF + f] = acc1;
        Wh[(size_t)(rr + 2) * FF + f] = acc2;
        Wh[(size_t)(rr + 3) * FF + f] = acc3;

        float a1 = a[f], a2 = a[64 + f];
        #pragma unroll
        for (int r = 0; r < 4; ++r) {
            float acc = (r == 0) ? acc0 : (r == 1) ? acc1 : (r == 2) ? acc2 : acc3;
            float v1 = acc * a1, v2 = acc * a2;
            #pragma unroll
            for (int off = 32; off; off >>= 1) {
                v1 += __shfl_down(v1, off, 64);
                v2 += __shfl_down(v2, off, 64);
            }
            if (f == 0) {
                if (br2 == 0) { s11[rr + r] = v1; s12[rr + r] = v2; }
                else          { s21[rr + r] = v1; s22[rr + r] = v2; }
            }
        }
    }
}

// ---------------- Kernel 2: fused attention, both hops, one block per row ----------------
__global__ __launch_bounds__(256) void attn_kernel(const u64* __restrict__ packA,
                                                   const float* __restrict__ Wh1,
                                                   const float* __restrict__ Wh2,
                                                   const float* __restrict__ s11,
                                                   const float* __restrict__ s12,
                                                   const float* __restrict__ s21,
                                                   const float* __restrict__ s22,
                                                   float* __restrict__ hp) {
    __shared__ int   nbr1[CAP1];
    __shared__ float ev1[CAP1];
    __shared__ int   nbr2[CAP2];
    __shared__ float ev2[CAP2];
    __shared__ u64   maskw[3 * 64];
    __shared__ float red[8];
    __shared__ float partial[1024];
    __shared__ int   scnt1, scnt2;

    int i = blockIdx.x;
    int tid = threadIdx.x;
    int w = tid >> 6, lane = tid & 63;

    // ---- build 1-hop list once (wave 0) ----
    if (w == 0) {
        int t1 = build_idx(packA[(size_t)i * 64 + lane], lane, CAP1, nbr1);
        if (lane == 0) scnt1 = t1;
    }
    __syncthreads();                                  // B1
    int c1 = min(scnt1, CAP1);

    if (c1 > 0) {
        if (w == 0) {
            // ---- hop-1 entirely in wave 0: softmax + vectorized gather ----
            int c1p = (c1 + 15) & ~15;
            for (int n = c1 + lane; n < c1p; n += 64) { nbr1[n] = 0; ev1[n] = 0.f; }
            float s11i = s11[i];
            float lm = -3.4e38f;
            for (int n = lane; n < c1; n += 64) {
                float e = lrelu(s11i + s12[nbr1[n]]);
                ev1[n] = e;
                lm = fmaxf(lm, e);
            }
            float m = wave_fmax(lm);
            float ls = 0.f;
            for (int n = lane; n < c1; n += 64) {
                float p = __expf(ev1[n] - m);
                ev1[n] = p;
                ls += p;
            }
            float invZ = 1.f / wave_fsum(ls);
            // 4 groups x 16 lanes, int4/float4 LDS reads, 32-bit addressing
            int g = lane >> 4, fq = (lane & 15) << 2;
            float ax = 0.f, ay = 0.f, az = 0.f, aw = 0.f;
            for (int n = g * 4; n < c1p; n += 16) {
                int4   nb = *(const int4*)&nbr1[n];
                float4 wv = *(const float4*)&ev1[n];
                float4 q0 = *(const float4*)&Wh1[nb.x * FF + fq];
                float4 q1 = *(const float4*)&Wh1[nb.y * FF + fq];
                float4 q2 = *(const float4*)&Wh1[nb.z * FF + fq];
                float4 q3 = *(const float4*)&Wh1[nb.w * FF + fq];
                ax += wv.x * q0.x + wv.y * q1.x + wv.z * q2.x + wv.w * q3.x;
                ay += wv.x * q0.y + wv.y * q1.y + wv.z * q2.y + wv.w * q3.y;
                az += wv.x * q0.z + wv.y * q1.z + wv.z * q2.z + wv.w * q3.z;
                aw += wv.x * q0.w + wv.y * q1.w + wv.z * q2.w + wv.w * q3.w;
            }
            // reduce across the 4 groups (lanes q, q+16, q+32, q+48)
            ax += __shfl_xor(ax, 16, 64); ax += __shfl_xor(ax, 32, 64);
            ay += __shfl_xor(ay, 16, 64); ay += __shfl_xor(ay, 32, 64);
            az += __shfl_xor(az, 16, 64); az += __shfl_xor(az, 32, 64);
            aw += __shfl_xor(aw, 16, 64); aw += __shfl_xor(aw, 32, 64);
            if (g == 0)
                *(float4*)&hp[(size_t)i * 128 + fq] =
                    make_float4(ax * invZ, ay * invZ, az * invZ, aw * invZ);
        } else {
            // ---- waves 1-3: 2-hop mask OR (overlaps wave-0 compute) ----
            u64 m = 0;
            for (int n = w - 1; n < c1; n += 3)
                m |= packA[nbr1[n] * 64 + lane];
            maskw[(w - 1) * 64 + lane] = m;
        }
    } else {
        // degenerate row: uniform attention over all NN (block-uniform branch)
        int g = tid >> 4, fq = (tid & 15) << 2;
        float ax = 0.f, ay = 0.f, az = 0.f, aw = 0.f;
        for (int n = g; n < NN; n += 16) {
            float4 v = *(const float4*)&Wh1[n * FF + fq];
            ax += v.x; ay += v.y; az += v.z; aw += v.w;
        }
        *(float4*)&partial[tid << 2] = make_float4(ax, ay, az, aw);
        if (w) maskw[(w - 1) * 64 + lane] = 0;
        __syncthreads();
        if (tid < 64) {
            float s = 0.f;
            #pragma unroll
            for (int g2 = 0; g2 < 16; ++g2) s += partial[g2 * 64 + tid];
            hp[(size_t)i * 128 + tid] = s * (1.f / NN);
        }
    }
    __syncthreads();                                  // B2: maskw ready

    // ---- combine mask, build 2-hop list (wave 0) ----
    if (w == 0) {
        u64 word = maskw[lane] | maskw[64 + lane] | maskw[128 + lane];
        if (lane == (i >> 6)) word &= ~(1ull << (i & 63));   // zero adj2 diagonal
        int t2 = build_idx(word, lane, CAP2, nbr2);
        if (lane == 0) scnt2 = t2;
    }
    __syncthreads();                                  // B3
    int c2 = min(scnt2, CAP2);
    int c2p = (c2 + 63) & ~63;

    float Z2inv;
    if (c2 > 0) {
        float s21i = s21[i];
        float lm = -3.4e38f;
        for (int n = tid; n < c2; n += 256) {
            float e = lrelu(s21i + s22[nbr2[n]]);
            ev2[n] = e;
            lm = fmaxf(lm, e);
        }
        lm = wave_fmax(lm);
        if (lane == 0) red[w] = lm;
        __syncthreads();                              // B4
        float mx = fmaxf(fmaxf(red[0], red[1]), fmaxf(red[2], red[3]));
        float ls = 0.f;
        for (int n = tid; n < c2; n += 256) {
            float p = __expf(ev2[n] - mx);
            ev2[n] = p;
            ls += p;
        }
        for (int n = c2 + tid; n < c2p; n += 256) { ev2[n] = 0.f; nbr2[n] = 0; }
        ls = wave_fsum(ls);
        if (lane == 0) red[4 + w] = ls;
        __syncthreads();                              // B5 (ev2 + pad also visible)
        Z2inv = 1.f / (red[4] + red[5] + red[6] + red[7]);
    } else {
        Z2inv = 1.f / (float)NN;
    }

    // ---- hop-2 gather: 16 groups x 16 lanes, int4/float4, 32-bit addressing ----
    int g = tid >> 4, fq = (tid & 15) << 2;
    float ax = 0.f, ay = 0.f, az = 0.f, aw = 0.f;
    if (c2 > 0) {
        for (int n = g * 4; n < c2p; n += 64) {
            int4   nb = *(const int4*)&nbr2[n];
            float4 wv = *(const float4*)&ev2[n];
            float4 q0 = *(const float4*)&Wh2[nb.x * FF + fq];
            float4 q1 = *(const float4*)&Wh2[nb.y * FF + fq];
            float4 q2 = *(const float4*)&Wh2[nb.z * FF + fq];
            float4 q3 = *(const float4*)&Wh2[nb.w * FF + fq];
            ax += wv.x * q0.x + wv.y * q1.x + wv.z * q2.x + wv.w * q3.x;
            ay += wv.x * q0.y + wv.y * q1.y + wv.z * q2.y + wv.w * q3.y;
            az += wv.x * q0.z + wv.y * q1.z + wv.z * q2.z + wv.w * q3.z;
            aw += wv.x * q0.w + wv.y * q1.w + wv.z * q2.w + wv.w * q3.w;
        }
    } else {
        for (int n = g; n < NN; n += 16) {
            float4 v = *(const float4*)&Wh2[n * FF + fq];
            ax += v.x; ay += v.y; az += v.z; aw += v.w;
        }
    }
    *(float4*)&partial[tid << 2] = make_float4(ax, ay, az, aw);
    __syncthreads();                                  // B6
    if (tid < 64) {
        float s = 0.f;
        #pragma unroll
        for (int g2 = 0; g2 < 16; ++g2) s += partial[g2 * 64 + tid];
        hp[(size_t)i * 128 + 64 + tid] = s * Z2inv;
    }
}

// ---------------- Kernel 3: per-block column partials ----------------
__global__ __launch_bounds__(256) void stats_kernel(const float* __restrict__ hp,
                                                    float* __restrict__ ps,
                                                    float* __restrict__ pq) {
    __shared__ float ls[128], lq[128];
    int tid = threadIdx.x;
    if (tid < 128) { ls[tid] = 0.f; lq[tid] = 0.f; }
    __syncthreads();
    float s0 = 0, s1 = 0, s2 = 0, s3 = 0, q0 = 0, q1 = 0, q2 = 0, q3 = 0;
    const float4* hp4 = (const float4*)hp;
    for (size_t idx = (size_t)blockIdx.x * 256 + tid; idx < (size_t)NN * 32;
         idx += (size_t)gridDim.x * 256) {
        float4 v = hp4[idx];
        s0 += v.x; q0 += v.x * v.x;
        s1 += v.y; q1 += v.y * v.y;
        s2 += v.z; q2 += v.z * v.z;
        s3 += v.w; q3 += v.w * v.w;
    }
    int cb = (tid & 31) << 2;
    atomicAdd(&ls[cb + 0], s0); atomicAdd(&lq[cb + 0], q0);
    atomicAdd(&ls[cb + 1], s1); atomicAdd(&lq[cb + 1], q1);
    atomicAdd(&ls[cb + 2], s2); atomicAdd(&lq[cb + 2], q2);
    atomicAdd(&ls[cb + 3], s3); atomicAdd(&lq[cb + 3], q3);
    __syncthreads();
    if (tid < 128) {
        ps[(size_t)blockIdx.x * 128 + tid] = ls[tid];
        pq[(size_t)blockIdx.x * 128 + tid] = lq[tid];
    }
}

// ---------------- Kernel 3b: finalize column stats ----------------
__global__ __launch_bounds__(256) void finalize_kernel(const float* __restrict__ ps,
                                                       const float* __restrict__ pq,
                                                       float* __restrict__ colsum,
                                                       float* __restrict__ colsq) {
    int tid = threadIdx.x;
    const float* src = (tid < 128) ? ps : pq;
    int c = tid & 127;
    float s = 0.f;
    #pragma unroll 8
    for (int b = 0; b < 256; ++b) s += src[(size_t)b * 128 + c];
    if (tid < 128) colsum[c] = s;
    else           colsq[c]  = s;
}

// ---------------- Kernel 4: batchnorm + lrelu ----------------
__global__ __launch_bounds__(256) void norm_kernel(float* __restrict__ hp,
                                                   const float* __restrict__ colsum,
                                                   const float* __restrict__ colsq,
                                                   const float* __restrict__ gamma,
                                                   const float* __restrict__ beta) {
    size_t idx = (size_t)blockIdx.x * 256 + threadIdx.x;
    if (idx >= (size_t)NN * 32) return;
    int cb = (int)((idx << 2) & 127);
    float4 v = ((const float4*)hp)[idx];
    float r[4] = {v.x, v.y, v.z, v.w};
    #pragma unroll
    for (int t = 0; t < 4; ++t) {
        int c = cb + t;
        float mean = colsum[c] * (1.f / NN);
        float var = colsq[c] * (1.f / NN) - mean * mean;
        float inv = rsqrtf(var + EPSV);
        r[t] = lrelu((r[t] - mean) * inv * gamma[c] + beta[c]);
    }
    ((float4*)hp)[idx] = make_float4(r[0], r[1], r[2], r[3]);
}

extern "C" void kernel_launch(void* const* d_in, const int* in_sizes, int n_in,
                              void* d_out, int out_size, void* d_ws, size_t ws_size,
                              hipStream_t stream) {
    const float* h     = (const float*)d_in[0];
    const float* adj   = (const float*)d_in[1];
    const float* W1    = (const float*)d_in[2];
    const float* W2    = (const float*)d_in[3];
    const float* a     = (const float*)d_in[4];
    const float* gamma = (const float*)d_in[5];
    const float* beta  = (const float*)d_in[6];
    float* hp = (float*)d_out;   // [4096, 128]

    u64* packA  = (u64*)d_ws;                         // 2 MB
    float* Wh1  = (float*)(packA + (size_t)NN * 64);  // 1 MB
    float* Wh2  = Wh1 + (size_t)NN * FF;              // 1 MB
    float* s11  = Wh2 + (size_t)NN * FF;
    float* s12  = s11 + NN;
    float* s21  = s12 + NN;
    float* s22  = s21 + NN;
    float* ps   = s22 + NN;                           // 256*128
    float* pq   = ps + 256 * 128;                     // 256*128
    float* colsum = pq + 256 * 128;                   // 128
    float* colsq  = colsum + 128;                     // 128

    packwh_kernel<<<NN + WHB, 256, 0, stream>>>(adj, packA, h, W1, W2, a,
                                                Wh1, Wh2, s11, s12, s21, s22);
    attn_kernel<<<NN, 256, 0, stream>>>(packA, Wh1, Wh2, s11, s12, s21, s22, hp);
    stats_kernel<<<256, 256, 0, stream>>>(hp, ps, pq);
    finalize_kernel<<<1, 256, 0, stream>>>(ps, pq, colsum, colsq);
    norm_kernel<<<(NN * 32 + 255) / 256, 256, 0, stream>>>(hp, colsum, colsq, gamma, beta);
}

// Round 6
// 173.356 us; speedup vs baseline: 1.0571x; 1.0571x over previous
//
#include <hip/hip_runtime.h>
#include <hip/hip_bf16.h>

#define NN 4096
#define IN_F 512
#define HALF 256
#define FF 64
#define ALPHA 0.2f
#define EPSV 1e-5f
#define CAP1 256
#define CAP2 1024

typedef unsigned long long u64;
typedef unsigned int u32;

__device__ __forceinline__ float lrelu(float x){ return x > 0.f ? x : ALPHA * x; }

__device__ __forceinline__ float wave_fmax(float v){
    #pragma unroll
    for (int off = 32; off; off >>= 1) v = fmaxf(v, __shfl_xor(v, off, 64));
    return v;
}
__device__ __forceinline__ float wave_fsum(float v){
    #pragma unroll
    for (int off = 32; off; off >>= 1) v += __shfl_xor(v, off, 64);
    return v;
}

// Wave-wide compaction of set bits (one u64 word per lane) into an index list.
__device__ __forceinline__ int build_idx(u64 bits, int lane, int cap, int* __restrict__ nbr){
    int pc = __popcll(bits);
    int scan = pc;
    #pragma unroll
    for (int off = 1; off < 64; off <<= 1) {
        int v = __shfl_up(scan, off, 64);
        if (lane >= off) scan += v;
    }
    int total = __shfl(scan, 63, 64);
    int pos = scan - pc;
    while (bits) {
        int b = __builtin_ctzll(bits);
        bits &= bits - 1;
        if (pos < cap) nbr[pos] = (lane << 6) | b;
        ++pos;
    }
    return total;
}

// ---------------- Kernel 1: bit-pack adjacency (float4 loads + shfl-OR word build) ----------------
// Thread t covers cols [4*idx, 4*idx+4). Word w (cols 64w..64w+63) is assembled from
// 16 consecutive lanes' nibbles via a 4-step u64 shfl_xor OR-reduce (no ballots).
__global__ __launch_bounds__(256) void pack_kernel(const float* __restrict__ adj,
                                                   u64* __restrict__ packA) {
    int i = blockIdx.x;
    int tid = threadIdx.x;
    int lane = tid & 63;
    int sh = (lane & 15) << 2;
    const float4* row = (const float4*)(adj + (size_t)i * NN);
    #pragma unroll
    for (int t = 0; t < 4; ++t) {
        int idx = t * 256 + tid;            // float4 index within the row
        float4 v = row[idx];
        u32 nib = (u32)(v.x > 0.f) | ((u32)(v.y > 0.f) << 1) |
                  ((u32)(v.z > 0.f) << 2) | ((u32)(v.w > 0.f) << 3);
        u64 word = (u64)nib << sh;
        word |= __shfl_xor(word, 1, 64);
        word |= __shfl_xor(word, 2, 64);
        word |= __shfl_xor(word, 4, 64);
        word |= __shfl_xor(word, 8, 64);
        if ((lane & 15) == 0)
            packA[(size_t)i * 64 + (idx >> 4)] = word;
    }
}

// ---------------- Kernel 2: Wh GEMV, 4 rows/block ----------------
__global__ __launch_bounds__(128) void wh_kernel(const float* __restrict__ h,
                                                 const float* __restrict__ W1,
                                                 const float* __restrict__ W2,
                                                 const float* __restrict__ a,
                                                 float* __restrict__ Wh1,
                                                 float* __restrict__ Wh2,
                                                 float* __restrict__ s11,
                                                 float* __restrict__ s12,
                                                 float* __restrict__ s21,
                                                 float* __restrict__ s22) {
    __shared__ float hs[4 * IN_F];
    int r0 = blockIdx.x * 4;
    int tid = threadIdx.x;
    const float4* hsrc = (const float4*)(h + (size_t)r0 * IN_F);
    float4* hdst = (float4*)hs;
    #pragma unroll
    for (int t = 0; t < 4; ++t) hdst[tid + 128 * t] = hsrc[tid + 128 * t];
    __syncthreads();

    int wave = tid >> 6, f = tid & 63;
    const float* W = wave ? W2 : W1;
    const float* hw = hs + wave * HALF;
    float acc0 = 0.f, acc1 = 0.f, acc2 = 0.f, acc3 = 0.f;
    #pragma unroll 4
    for (int k = 0; k < HALF; ++k) {
        float w = W[k * FF + f];
        acc0 += hw[k] * w;
        acc1 += hw[IN_F + k] * w;
        acc2 += hw[2 * IN_F + k] * w;
        acc3 += hw[3 * IN_F + k] * w;
    }
    float* Wh = wave ? Wh2 : Wh1;
    Wh[(size_t)(r0 + 0) * FF + f] = acc0;
    Wh[(size_t)(r0 + 1) * FF + f] = acc1;
    Wh[(size_t)(r0 + 2) * FF + f] = acc2;
    Wh[(size_t)(r0 + 3) * FF + f] = acc3;

    float a1 = a[f], a2 = a[64 + f];
    #pragma unroll
    for (int r = 0; r < 4; ++r) {
        float acc = (r == 0) ? acc0 : (r == 1) ? acc1 : (r == 2) ? acc2 : acc3;
        float v1 = acc * a1, v2 = acc * a2;
        #pragma unroll
        for (int off = 32; off; off >>= 1) {
            v1 += __shfl_down(v1, off, 64);
            v2 += __shfl_down(v2, off, 64);
        }
        if (f == 0) {
            if (wave == 0) { s11[r0 + r] = v1; s12[r0 + r] = v2; }
            else           { s21[r0 + r] = v1; s22[r0 + r] = v2; }
        }
    }
}

// ---------------- Kernel 3: fused attention, both hops, one block per row ----------------
__global__ __launch_bounds__(256) void attn_kernel(const u64* __restrict__ packA,
                                                   const float* __restrict__ Wh1,
                                                   const float* __restrict__ Wh2,
                                                   const float* __restrict__ s11,
                                                   const float* __restrict__ s12,
                                                   const float* __restrict__ s21,
                                                   const float* __restrict__ s22,
                                                   float* __restrict__ hp) {
    __shared__ int   nbr1[CAP1];
    __shared__ float ev1[CAP1];
    __shared__ int   nbr2[CAP2];
    __shared__ float ev2[CAP2];
    __shared__ u64   maskw[3 * 64];
    __shared__ float red[8];
    __shared__ float partial[1024];
    __shared__ int   scnt1, scnt2;

    int i = blockIdx.x;
    int tid = threadIdx.x;
    int w = tid >> 6, lane = tid & 63;

    // ---- build 1-hop list once (wave 0) ----
    if (w == 0) {
        int t1 = build_idx(packA[(size_t)i * 64 + lane], lane, CAP1, nbr1);
        if (lane == 0) scnt1 = t1;
    }
    __syncthreads();                                  // B1
    int c1 = min(scnt1, CAP1);

    if (c1 > 0) {
        if (w == 0) {
            // ---- hop-1 entirely in wave 0: softmax + vectorized gather ----
            int c1p = (c1 + 15) & ~15;
            for (int n = c1 + lane; n < c1p; n += 64) { nbr1[n] = 0; ev1[n] = 0.f; }
            float s11i = s11[i];
            float lm = -3.4e38f;
            for (int n = lane; n < c1; n += 64) {
                float e = lrelu(s11i + s12[nbr1[n]]);
                ev1[n] = e;
                lm = fmaxf(lm, e);
            }
            float m = wave_fmax(lm);
            float ls = 0.f;
            for (int n = lane; n < c1; n += 64) {
                float p = __expf(ev1[n] - m);
                ev1[n] = p;
                ls += p;
            }
            float invZ = 1.f / wave_fsum(ls);
            int g = lane >> 4, fq = (lane & 15) << 2;
            float ax = 0.f, ay = 0.f, az = 0.f, aw = 0.f;
            for (int n = g * 4; n < c1p; n += 16) {
                int4   nb = *(const int4*)&nbr1[n];
                float4 wv = *(const float4*)&ev1[n];
                float4 q0 = *(const float4*)&Wh1[nb.x * FF + fq];
                float4 q1 = *(const float4*)&Wh1[nb.y * FF + fq];
                float4 q2 = *(const float4*)&Wh1[nb.z * FF + fq];
                float4 q3 = *(const float4*)&Wh1[nb.w * FF + fq];
                ax += wv.x * q0.x + wv.y * q1.x + wv.z * q2.x + wv.w * q3.x;
                ay += wv.x * q0.y + wv.y * q1.y + wv.z * q2.y + wv.w * q3.y;
                az += wv.x * q0.z + wv.y * q1.z + wv.z * q2.z + wv.w * q3.z;
                aw += wv.x * q0.w + wv.y * q1.w + wv.z * q2.w + wv.w * q3.w;
            }
            ax += __shfl_xor(ax, 16, 64); ax += __shfl_xor(ax, 32, 64);
            ay += __shfl_xor(ay, 16, 64); ay += __shfl_xor(ay, 32, 64);
            az += __shfl_xor(az, 16, 64); az += __shfl_xor(az, 32, 64);
            aw += __shfl_xor(aw, 16, 64); aw += __shfl_xor(aw, 32, 64);
            if (g == 0)
                *(float4*)&hp[(size_t)i * 128 + fq] =
                    make_float4(ax * invZ, ay * invZ, az * invZ, aw * invZ);
        } else {
            // ---- waves 1-3: 2-hop mask OR (overlaps wave-0 compute) ----
            u64 m = 0;
            for (int n = w - 1; n < c1; n += 3)
                m |= packA[nbr1[n] * 64 + lane];
            maskw[(w - 1) * 64 + lane] = m;
        }
    } else {
        // degenerate row: uniform attention over all NN (block-uniform branch)
        int g = tid >> 4, fq = (tid & 15) << 2;
        float ax = 0.f, ay = 0.f, az = 0.f, aw = 0.f;
        for (int n = g; n < NN; n += 16) {
            float4 v = *(const float4*)&Wh1[n * FF + fq];
            ax += v.x; ay += v.y; az += v.z; aw += v.w;
        }
        *(float4*)&partial[tid << 2] = make_float4(ax, ay, az, aw);
        if (w) maskw[(w - 1) * 64 + lane] = 0;
        __syncthreads();
        if (tid < 64) {
            float s = 0.f;
            #pragma unroll
            for (int g2 = 0; g2 < 16; ++g2) s += partial[g2 * 64 + tid];
            hp[(size_t)i * 128 + tid] = s * (1.f / NN);
        }
    }
    __syncthreads();                                  // B2: maskw ready

    // ---- combine mask, build 2-hop list (wave 0) ----
    if (w == 0) {
        u64 word = maskw[lane] | maskw[64 + lane] | maskw[128 + lane];
        if (lane == (i >> 6)) word &= ~(1ull << (i & 63));   // zero adj2 diagonal
        int t2 = build_idx(word, lane, CAP2, nbr2);
        if (lane == 0) scnt2 = t2;
    }
    __syncthreads();                                  // B3
    int c2 = min(scnt2, CAP2);
    int c2p = (c2 + 63) & ~63;

    float Z2inv;
    if (c2 > 0) {
        float s21i = s21[i];
        float lm = -3.4e38f;
        for (int n = tid; n < c2; n += 256) {
            float e = lrelu(s21i + s22[nbr2[n]]);
            ev2[n] = e;
            lm = fmaxf(lm, e);
        }
        lm = wave_fmax(lm);
        if (lane == 0) red[w] = lm;
        __syncthreads();                              // B4
        float mx = fmaxf(fmaxf(red[0], red[1]), fmaxf(red[2], red[3]));
        float ls = 0.f;
        for (int n = tid; n < c2; n += 256) {
            float p = __expf(ev2[n] - mx);
            ev2[n] = p;
            ls += p;
        }
        for (int n = c2 + tid; n < c2p; n += 256) { ev2[n] = 0.f; nbr2[n] = 0; }
        ls = wave_fsum(ls);
        if (lane == 0) red[4 + w] = ls;
        __syncthreads();                              // B5 (ev2 + pad also visible)
        Z2inv = 1.f / (red[4] + red[5] + red[6] + red[7]);
    } else {
        Z2inv = 1.f / (float)NN;
    }

    // ---- hop-2 gather: 16 groups x 16 lanes, int4/float4, 32-bit addressing ----
    int g = tid >> 4, fq = (tid & 15) << 2;
    float ax = 0.f, ay = 0.f, az = 0.f, aw = 0.f;
    if (c2 > 0) {
        for (int n = g * 4; n < c2p; n += 64) {
            int4   nb = *(const int4*)&nbr2[n];
            float4 wv = *(const float4*)&ev2[n];
            float4 q0 = *(const float4*)&Wh2[nb.x * FF + fq];
            float4 q1 = *(const float4*)&Wh2[nb.y * FF + fq];
            float4 q2 = *(const float4*)&Wh2[nb.z * FF + fq];
            float4 q3 = *(const float4*)&Wh2[nb.w * FF + fq];
            ax += wv.x * q0.x + wv.y * q1.x + wv.z * q2.x + wv.w * q3.x;
            ay += wv.x * q0.y + wv.y * q1.y + wv.z * q2.y + wv.w * q3.y;
            az += wv.x * q0.z + wv.y * q1.z + wv.z * q2.z + wv.w * q3.z;
            aw += wv.x * q0.w + wv.y * q1.w + wv.z * q2.w + wv.w * q3.w;
        }
    } else {
        for (int n = g; n < NN; n += 16) {
            float4 v = *(const float4*)&Wh2[n * FF + fq];
            ax += v.x; ay += v.y; az += v.z; aw += v.w;
        }
    }
    *(float4*)&partial[tid << 2] = make_float4(ax, ay, az, aw);
    __syncthreads();                                  // B6
    if (tid < 64) {
        float s = 0.f;
        #pragma unroll
        for (int g2 = 0; g2 < 16; ++g2) s += partial[g2 * 64 + tid];
        hp[(size_t)i * 128 + 64 + tid] = s * Z2inv;
    }
}

// ---------------- Kernel 4: per-block column partials ----------------
__global__ __launch_bounds__(256) void stats_kernel(const float* __restrict__ hp,
                                                    float* __restrict__ ps,
                                                    float* __restrict__ pq) {
    __shared__ float ls[128], lq[128];
    int tid = threadIdx.x;
    if (tid < 128) { ls[tid] = 0.f; lq[tid] = 0.f; }
    __syncthreads();
    float s0 = 0, s1 = 0, s2 = 0, s3 = 0, q0 = 0, q1 = 0, q2 = 0, q3 = 0;
    const float4* hp4 = (const float4*)hp;
    for (size_t idx = (size_t)blockIdx.x * 256 + tid; idx < (size_t)NN * 32;
         idx += (size_t)gridDim.x * 256) {
        float4 v = hp4[idx];
        s0 += v.x; q0 += v.x * v.x;
        s1 += v.y; q1 += v.y * v.y;
        s2 += v.z; q2 += v.z * v.z;
        s3 += v.w; q3 += v.w * v.w;
    }
    int cb = (tid & 31) << 2;
    atomicAdd(&ls[cb + 0], s0); atomicAdd(&lq[cb + 0], q0);
    atomicAdd(&ls[cb + 1], s1); atomicAdd(&lq[cb + 1], q1);
    atomicAdd(&ls[cb + 2], s2); atomicAdd(&lq[cb + 2], q2);
    atomicAdd(&ls[cb + 3], s3); atomicAdd(&lq[cb + 3], q3);
    __syncthreads();
    if (tid < 128) {
        ps[(size_t)blockIdx.x * 128 + tid] = ls[tid];
        pq[(size_t)blockIdx.x * 128 + tid] = lq[tid];
    }
}

// ---------------- Kernel 4b: finalize column stats ----------------
__global__ __launch_bounds__(256) void finalize_kernel(const float* __restrict__ ps,
                                                       const float* __restrict__ pq,
                                                       float* __restrict__ colsum,
                                                       float* __restrict__ colsq) {
    int tid = threadIdx.x;
    const float* src = (tid < 128) ? ps : pq;
    int c = tid & 127;
    float s = 0.f;
    #pragma unroll 8
    for (int b = 0; b < 256; ++b) s += src[(size_t)b * 128 + c];
    if (tid < 128) colsum[c] = s;
    else           colsq[c]  = s;
}

// ---------------- Kernel 5: batchnorm + lrelu ----------------
__global__ __launch_bounds__(256) void norm_kernel(float* __restrict__ hp,
                                                   const float* __restrict__ colsum,
                                                   const float* __restrict__ colsq,
                                                   const float* __restrict__ gamma,
                                                   const float* __restrict__ beta) {
    size_t idx = (size_t)blockIdx.x * 256 + threadIdx.x;
    if (idx >= (size_t)NN * 32) return;
    int cb = (int)((idx << 2) & 127);
    float4 v = ((const float4*)hp)[idx];
    float r[4] = {v.x, v.y, v.z, v.w};
    #pragma unroll
    for (int t = 0; t < 4; ++t) {
        int c = cb + t;
        float mean = colsum[c] * (1.f / NN);
        float var = colsq[c] * (1.f / NN) - mean * mean;
        float inv = rsqrtf(var + EPSV);
        r[t] = lrelu((r[t] - mean) * inv * gamma[c] + beta[c]);
    }
    ((float4*)hp)[idx] = make_float4(r[0], r[1], r[2], r[3]);
}

extern "C" void kernel_launch(void* const* d_in, const int* in_sizes, int n_in,
                              void* d_out, int out_size, void* d_ws, size_t ws_size,
                              hipStream_t stream) {
    const float* h     = (const float*)d_in[0];
    const float* adj   = (const float*)d_in[1];
    const float* W1    = (const float*)d_in[2];
    const float* W2    = (const float*)d_in[3];
    const float* a     = (const float*)d_in[4];
    const float* gamma = (const float*)d_in[5];
    const float* beta  = (const float*)d_in[6];
    float* hp = (float*)d_out;   // [4096, 128]

    u64* packA  = (u64*)d_ws;                         // 2 MB
    float* Wh1  = (float*)(packA + (size_t)NN * 64);  // 1 MB
    float* Wh2  = Wh1 + (size_t)NN * FF;              // 1 MB
    float* s11  = Wh2 + (size_t)NN * FF;
    float* s12  = s11 + NN;
    float* s21  = s12 + NN;
    float* s22  = s21 + NN;
    float* ps   = s22 + NN;                           // 256*128
    float* pq   = ps + 256 * 128;                     // 256*128
    float* colsum = pq + 256 * 128;                   // 128
    float* colsq  = colsum + 128;                     // 128

    pack_kernel<<<NN, 256, 0, stream>>>(adj, packA);
    wh_kernel<<<NN / 4, 128, 0, stream>>>(h, W1, W2, a, Wh1, Wh2, s11, s12, s21, s22);
    attn_kernel<<<NN, 256, 0, stream>>>(packA, Wh1, Wh2, s11, s12, s21, s22, hp);
    stats_kernel<<<256, 256, 0, stream>>>(hp, ps, pq);
    finalize_kernel<<<1, 256, 0, stream>>>(ps, pq, colsum, colsq);
    norm_kernel<<<(NN * 32 + 255) / 256, 256, 0, stream>>>(hp, colsum, colsq, gamma, beta);
}

// Round 7
// 168.890 us; speedup vs baseline: 1.0851x; 1.0264x over previous
//
#include <hip/hip_runtime.h>
#include <hip/hip_bf16.h>

#define NN 4096
#define IN_F 512
#define HALF 256
#define FF 64
#define ALPHA 0.2f
#define EPSV 1e-5f
#define CAP1 128
#define CAP2 1024
#define WHB (NN / 8)

typedef unsigned long long u64;
typedef unsigned int u32;
typedef unsigned short u16;

__device__ __forceinline__ float lrelu(float x){ return x > 0.f ? x : ALPHA * x; }

__device__ __forceinline__ float wave_fmax(float v){
    #pragma unroll
    for (int off = 32; off; off >>= 1) v = fmaxf(v, __shfl_xor(v, off, 64));
    return v;
}
__device__ __forceinline__ float wave_fsum(float v){
    #pragma unroll
    for (int off = 32; off; off >>= 1) v += __shfl_xor(v, off, 64);
    return v;
}

// Wave-wide compaction of set bits (one u64 word per lane) into a u16 index list.
__device__ __forceinline__ int build_idx16(u64 bits, int lane, int cap, u16* __restrict__ nbr){
    int pc = __popcll(bits);
    int scan = pc;
    #pragma unroll
    for (int off = 1; off < 64; off <<= 1) {
        int v = __shfl_up(scan, off, 64);
        if (lane >= off) scan += v;
    }
    int total = __shfl(scan, 63, 64);
    int pos = scan - pc;
    while (bits) {
        int b = __builtin_ctzll(bits);
        bits &= bits - 1;
        if (pos < cap) nbr[pos] = (u16)((lane << 6) | b);
        ++pos;
    }
    return total;
}

// ---------------- Kernel 1: fused pack (blocks < NN) + wh GEMV (blocks >= NN) ----------------
// pack is HBM-BW-bound; wh is L2/VALU-bound -> co-resident blocks overlap.
__global__ __launch_bounds__(256) void packwh_kernel(const float* __restrict__ adj,
                                                     u64* __restrict__ packA,
                                                     const float* __restrict__ h,
                                                     const float* __restrict__ W1,
                                                     const float* __restrict__ W2,
                                                     const float* __restrict__ a,
                                                     float* __restrict__ Wh1,
                                                     float* __restrict__ Wh2,
                                                     float* __restrict__ s11,
                                                     float* __restrict__ s12,
                                                     float* __restrict__ s21,
                                                     float* __restrict__ s22) {
    __shared__ float hs[8 * IN_F];   // 16 KB (wh branch only; pack occupancy is wave-capped anyway)
    int tid = threadIdx.x;
    if (blockIdx.x < NN) {
        // ---- pack: float4 loads + shfl-OR word assembly (no ballots) ----
        int i = blockIdx.x;
        int lane = tid & 63;
        int sh = (lane & 15) << 2;
        const float4* row = (const float4*)(adj + (size_t)i * NN);
        #pragma unroll
        for (int t = 0; t < 4; ++t) {
            int idx = t * 256 + tid;
            float4 v = row[idx];
            u32 nib = (u32)(v.x > 0.f) | ((u32)(v.y > 0.f) << 1) |
                      ((u32)(v.z > 0.f) << 2) | ((u32)(v.w > 0.f) << 3);
            u64 word = (u64)nib << sh;
            word |= __shfl_xor(word, 1, 64);
            word |= __shfl_xor(word, 2, 64);
            word |= __shfl_xor(word, 4, 64);
            word |= __shfl_xor(word, 8, 64);
            if ((lane & 15) == 0)
                packA[(size_t)i * 64 + (idx >> 4)] = word;
        }
    } else {
        // ---- wh: 8 rows per block; waves 0-1 -> W1, waves 2-3 -> W2 ----
        int r0 = (blockIdx.x - NN) * 8;
        const float4* hsrc = (const float4*)(h + (size_t)r0 * IN_F);
        float4* hdst = (float4*)hs;
        #pragma unroll
        for (int t = 0; t < 4; ++t) hdst[tid + 256 * t] = hsrc[tid + 256 * t];
        __syncthreads();

        int w = tid >> 6, f = tid & 63;
        int br2 = w >> 1;
        int rbase = (w & 1) * 4;
        const float* W = br2 ? W2 : W1;
        const float* hw = hs + rbase * IN_F + br2 * HALF;
        float acc0 = 0.f, acc1 = 0.f, acc2 = 0.f, acc3 = 0.f;
        #pragma unroll 4
        for (int k = 0; k < HALF; ++k) {
            float wt = W[k * FF + f];
            acc0 += hw[k] * wt;
            acc1 += hw[IN_F + k] * wt;
            acc2 += hw[2 * IN_F + k] * wt;
            acc3 += hw[3 * IN_F + k] * wt;
        }
        float* Wh = br2 ? Wh2 : Wh1;
        int rr = r0 + rbase;
        Wh[(size_t)(rr + 0) * FF + f] = acc0;
        Wh[(size_t)(rr + 1) * FF + f] = acc1;
        Wh[(size_t)(rr + 2) * FF + f] = acc2;
        Wh[(size_t)(rr + 3) * FF + f] = acc3;

        float a1 = a[f], a2 = a[64 + f];
        #pragma unroll
        for (int r = 0; r < 4; ++r) {
            float acc = (r == 0) ? acc0 : (r == 1) ? acc1 : (r == 2) ? acc2 : acc3;
            float v1 = acc * a1, v2 = acc * a2;
            #pragma unroll
            for (int off = 32; off; off >>= 1) {
                v1 += __shfl_down(v1, off, 64);
                v2 += __shfl_down(v2, off, 64);
            }
            if (f == 0) {
                if (br2 == 0) { s11[rr + r] = v1; s12[rr + r] = v2; }
                else          { s21[rr + r] = v1; s22[rr + r] = v2; }
            }
        }
    }
}

// ---------------- Kernel 2: fused attention, wave-local (1 wave = 1 row, both hops) ----------------
// Zero block barriers: each wave owns its LDS slice; softmax via shfl; mask word in register.
__global__ __launch_bounds__(256) void attn_kernel(const u64* __restrict__ packA,
                                                   const float* __restrict__ Wh1,
                                                   const float* __restrict__ Wh2,
                                                   const float* __restrict__ s11,
                                                   const float* __restrict__ s12,
                                                   const float* __restrict__ s21,
                                                   const float* __restrict__ s22,
                                                   float* __restrict__ hp) {
    __shared__ u16   nbr1s[4][CAP1];   // 1 KB
    __shared__ u16   nbr2s[4][CAP2];   // 8 KB
    __shared__ float evs[4][CAP2];     // 16 KB

    int tid = threadIdx.x;
    int w = tid >> 6, lane = tid & 63;
    int i = blockIdx.x * 4 + w;

    u16*   nbr1 = nbr1s[w];
    u16*   nbr2 = nbr2s[w];
    float* ev   = evs[w];

    // ---- 1-hop list ----
    int t1 = build_idx16(packA[(size_t)i * 64 + lane], lane, CAP1, nbr1);
    int c1 = min(t1, CAP1);

    // ---- hop-1: softmax + gather (lane = column) ----
    float out1;
    if (c1 > 0) {
        int c1p = (c1 + 3) & ~3;
        if (lane < c1p - c1) { nbr1[c1 + lane] = 0; }
        float s11i = s11[i];
        float lm = -3.4e38f;
        for (int n = lane; n < c1; n += 64) {
            float e = lrelu(s11i + s12[nbr1[n]]);
            ev[n] = e;
            lm = fmaxf(lm, e);
        }
        float m = wave_fmax(lm);
        float ls = 0.f;
        for (int n = lane; n < c1; n += 64) {
            float p = __expf(ev[n] - m);
            ev[n] = p;
            ls += p;
        }
        float invZ = 1.f / wave_fsum(ls);
        if (lane < c1p - c1) { ev[c1 + lane] = 0.f; }
        float a0 = 0.f, a1 = 0.f, a2 = 0.f, a3 = 0.f;
        for (int n = 0; n < c1p; n += 4) {
            ushort4 nb = *(const ushort4*)&nbr1[n];     // uniform LDS broadcast
            float4  wv = *(const float4*)&ev[n];
            a0 += wv.x * Wh1[(int)nb.x * FF + lane];
            a1 += wv.y * Wh1[(int)nb.y * FF + lane];
            a2 += wv.z * Wh1[(int)nb.z * FF + lane];
            a3 += wv.w * Wh1[(int)nb.w * FF + lane];
        }
        out1 = (a0 + a1 + a2 + a3) * invZ;
    } else {
        float a0 = 0.f, a1 = 0.f;
        for (int n = 0; n < NN; n += 2) {
            a0 += Wh1[n * FF + lane];
            a1 += Wh1[(n + 1) * FF + lane];
        }
        out1 = (a0 + a1) * (1.f / NN);
    }
    hp[(size_t)i * 128 + lane] = out1;

    // ---- 2-hop mask: OR of neighbor bit-rows (word per lane, in register) ----
    u64 word = 0;
    for (int n = 0; n < c1; ++n)
        word |= packA[(size_t)nbr1[n] * 64 + lane];
    if (lane == (i >> 6)) word &= ~(1ull << (i & 63));   // zero adj2 diagonal

    int t2 = build_idx16(word, lane, CAP2, nbr2);
    int c2 = min(t2, CAP2);

    // ---- hop-2: softmax + gather ----
    float out2;
    if (c2 > 0) {
        int c2p = (c2 + 3) & ~3;
        if (lane < c2p - c2) { nbr2[c2 + lane] = 0; }
        float s21i = s21[i];
        float lm = -3.4e38f;
        for (int n = lane; n < c2; n += 64) {
            float e = lrelu(s21i + s22[nbr2[n]]);
            ev[n] = e;
            lm = fmaxf(lm, e);
        }
        float m = wave_fmax(lm);
        float ls = 0.f;
        for (int n = lane; n < c2; n += 64) {
            float p = __expf(ev[n] - m);
            ev[n] = p;
            ls += p;
        }
        float invZ = 1.f / wave_fsum(ls);
        if (lane < c2p - c2) { ev[c2 + lane] = 0.f; }
        float a0 = 0.f, a1 = 0.f, a2 = 0.f, a3 = 0.f;
        for (int n = 0; n < c2p; n += 4) {
            ushort4 nb = *(const ushort4*)&nbr2[n];
            float4  wv = *(const float4*)&ev[n];
            a0 += wv.x * Wh2[(int)nb.x * FF + lane];
            a1 += wv.y * Wh2[(int)nb.y * FF + lane];
            a2 += wv.z * Wh2[(int)nb.z * FF + lane];
            a3 += wv.w * Wh2[(int)nb.w * FF + lane];
        }
        out2 = (a0 + a1 + a2 + a3) * invZ;
    } else {
        float a0 = 0.f, a1 = 0.f;
        for (int n = 0; n < NN; n += 2) {
            a0 += Wh2[n * FF + lane];
            a1 += Wh2[(n + 1) * FF + lane];
        }
        out2 = (a0 + a1) * (1.f / NN);
    }
    hp[(size_t)i * 128 + 64 + lane] = out2;
}

// ---------------- Kernel 3: per-block column partials (128 blocks) ----------------
__global__ __launch_bounds__(256) void stats_kernel(const float* __restrict__ hp,
                                                    float* __restrict__ ps,
                                                    float* __restrict__ pq) {
    __shared__ float ls[128], lq[128];
    int tid = threadIdx.x;
    if (tid < 128) { ls[tid] = 0.f; lq[tid] = 0.f; }
    __syncthreads();
    float s0 = 0, s1 = 0, s2 = 0, s3 = 0, q0 = 0, q1 = 0, q2 = 0, q3 = 0;
    const float4* hp4 = (const float4*)hp;
    for (size_t idx = (size_t)blockIdx.x * 256 + tid; idx < (size_t)NN * 32;
         idx += (size_t)gridDim.x * 256) {
        float4 v = hp4[idx];
        s0 += v.x; q0 += v.x * v.x;
        s1 += v.y; q1 += v.y * v.y;
        s2 += v.z; q2 += v.z * v.z;
        s3 += v.w; q3 += v.w * v.w;
    }
    int cb = (tid & 31) << 2;
    atomicAdd(&ls[cb + 0], s0); atomicAdd(&lq[cb + 0], q0);
    atomicAdd(&ls[cb + 1], s1); atomicAdd(&lq[cb + 1], q1);
    atomicAdd(&ls[cb + 2], s2); atomicAdd(&lq[cb + 2], q2);
    atomicAdd(&ls[cb + 3], s3); atomicAdd(&lq[cb + 3], q3);
    __syncthreads();
    if (tid < 128) {
        ps[(size_t)blockIdx.x * 128 + tid] = ls[tid];
        pq[(size_t)blockIdx.x * 128 + tid] = lq[tid];
    }
}

// ---------------- Kernel 4: finalize (per-block re-reduce) + batchnorm + lrelu ----------------
__global__ __launch_bounds__(256) void normf_kernel(float* __restrict__ hp,
                                                    const float* __restrict__ ps,
                                                    const float* __restrict__ pq,
                                                    const float* __restrict__ gamma,
                                                    const float* __restrict__ beta) {
    __shared__ float csum[256];
    __shared__ float cmean[128], cginv[128];
    int tid = threadIdx.x;
    {
        const float* src = (tid < 128) ? ps : pq;
        int c = tid & 127;
        float s = 0.f;
        #pragma unroll 8
        for (int b = 0; b < 128; ++b) s += src[b * 128 + c];
        csum[tid] = s;
    }
    __syncthreads();
    if (tid < 128) {
        float mean = csum[tid] * (1.f / NN);
        float var = csum[128 + tid] * (1.f / NN) - mean * mean;
        cmean[tid] = mean;
        cginv[tid] = rsqrtf(var + EPSV) * gamma[tid];
    }
    __syncthreads();

    size_t idx = (size_t)blockIdx.x * 256 + tid;
    if (idx < (size_t)NN * 32) {
        int cb = (int)((idx << 2) & 127);
        float4 v = ((const float4*)hp)[idx];
        float r[4] = {v.x, v.y, v.z, v.w};
        #pragma unroll
        for (int t = 0; t < 4; ++t) {
            int c = cb + t;
            r[t] = lrelu((r[t] - cmean[c]) * cginv[c] + beta[c]);
        }
        ((float4*)hp)[idx] = make_float4(r[0], r[1], r[2], r[3]);
    }
}

extern "C" void kernel_launch(void* const* d_in, const int* in_sizes, int n_in,
                              void* d_out, int out_size, void* d_ws, size_t ws_size,
                              hipStream_t stream) {
    const float* h     = (const float*)d_in[0];
    const float* adj   = (const float*)d_in[1];
    const float* W1    = (const float*)d_in[2];
    const float* W2    = (const float*)d_in[3];
    const float* a     = (const float*)d_in[4];
    const float* gamma = (const float*)d_in[5];
    const float* beta  = (const float*)d_in[6];
    float* hp = (float*)d_out;   // [4096, 128]

    u64* packA  = (u64*)d_ws;                         // 2 MB
    float* Wh1  = (float*)(packA + (size_t)NN * 64);  // 1 MB
    float* Wh2  = Wh1 + (size_t)NN * FF;              // 1 MB
    float* s11  = Wh2 + (size_t)NN * FF;
    float* s12  = s11 + NN;
    float* s21  = s12 + NN;
    float* s22  = s21 + NN;
    float* ps   = s22 + NN;                           // 128*128
    float* pq   = ps + 128 * 128;                     // 128*128

    packwh_kernel<<<NN + WHB, 256, 0, stream>>>(adj, packA, h, W1, W2, a,
                                                Wh1, Wh2, s11, s12, s21, s22);
    attn_kernel<<<NN / 4, 256, 0, stream>>>(packA, Wh1, Wh2, s11, s12, s21, s22, hp);
    stats_kernel<<<128, 256, 0, stream>>>(hp, ps, pq);
    normf_kernel<<<(NN * 32 + 255) / 256, 256, 0, stream>>>(hp, ps, pq, gamma, beta);
}

// Round 8
// 165.304 us; speedup vs baseline: 1.1086x; 1.0217x over previous
//
#include <hip/hip_runtime.h>
#include <hip/hip_bf16.h>

#define NN 4096
#define IN_F 512
#define HALF 256
#define FF 64
#define ALPHA 0.2f
#define EPSV 1e-5f
#define CAP1 128
#define CAP2 1024
#define WHB (NN / 8)

typedef unsigned long long u64;
typedef unsigned int u32;
typedef unsigned short u16;

__device__ __forceinline__ float lrelu(float x){ return x > 0.f ? x : ALPHA * x; }

__device__ __forceinline__ float wave_fmax(float v){
    #pragma unroll
    for (int off = 32; off; off >>= 1) v = fmaxf(v, __shfl_xor(v, off, 64));
    return v;
}
__device__ __forceinline__ float wave_fsum(float v){
    #pragma unroll
    for (int off = 32; off; off >>= 1) v += __shfl_xor(v, off, 64);
    return v;
}

// Wave-wide compaction of set bits (one u64 word per lane) into a u16 index list.
__device__ __forceinline__ int build_idx16(u64 bits, int lane, int cap, u16* __restrict__ nbr){
    int pc = __popcll(bits);
    int scan = pc;
    #pragma unroll
    for (int off = 1; off < 64; off <<= 1) {
        int v = __shfl_up(scan, off, 64);
        if (lane >= off) scan += v;
    }
    int total = __shfl(scan, 63, 64);
    int pos = scan - pc;
    while (bits) {
        int b = __builtin_ctzll(bits);
        bits &= bits - 1;
        if (pos < cap) nbr[pos] = (u16)((lane << 6) | b);
        ++pos;
    }
    return total;
}

// ---------------- Kernel 1: fused pack (blocks < NN) + wh GEMV (blocks >= NN) ----------------
// pack: thread t owns 16 CONTIGUOUS cols of one row -> one u16 word. 4 independent
// float4 loads hoisted (full MLP), no cross-lane ops at all. Layout of pack16 as
// little-endian u16[256] per row is bit-identical to the u64[64] view consumers read.
__global__ __launch_bounds__(256) void packwh_kernel(const float* __restrict__ adj,
                                                     u16* __restrict__ pack16,
                                                     const float* __restrict__ h,
                                                     const float* __restrict__ W1,
                                                     const float* __restrict__ W2,
                                                     const float* __restrict__ a,
                                                     float* __restrict__ Wh1,
                                                     float* __restrict__ Wh2,
                                                     float* __restrict__ s11,
                                                     float* __restrict__ s12,
                                                     float* __restrict__ s21,
                                                     float* __restrict__ s22) {
    __shared__ float hs[8 * IN_F];   // wh branch only
    int tid = threadIdx.x;
    if (blockIdx.x < NN) {
        int i = blockIdx.x;
        const float4* row = (const float4*)(adj + (size_t)i * NN);
        int t4 = tid << 2;
        float4 v0 = row[t4 + 0];
        float4 v1 = row[t4 + 1];
        float4 v2 = row[t4 + 2];
        float4 v3 = row[t4 + 3];
        u32 b0 = (u32)(v0.x > 0.f) | ((u32)(v0.y > 0.f) << 1) | ((u32)(v0.z > 0.f) << 2) | ((u32)(v0.w > 0.f) << 3);
        u32 b1 = (u32)(v1.x > 0.f) | ((u32)(v1.y > 0.f) << 1) | ((u32)(v1.z > 0.f) << 2) | ((u32)(v1.w > 0.f) << 3);
        u32 b2 = (u32)(v2.x > 0.f) | ((u32)(v2.y > 0.f) << 1) | ((u32)(v2.z > 0.f) << 2) | ((u32)(v2.w > 0.f) << 3);
        u32 b3 = (u32)(v3.x > 0.f) | ((u32)(v3.y > 0.f) << 1) | ((u32)(v3.z > 0.f) << 2) | ((u32)(v3.w > 0.f) << 3);
        pack16[(size_t)i * 256 + tid] = (u16)(b0 | (b1 << 4) | (b2 << 8) | (b3 << 12));
    } else {
        // ---- wh: 8 rows per block; waves 0-1 -> W1, waves 2-3 -> W2 ----
        int r0 = (blockIdx.x - NN) * 8;
        const float4* hsrc = (const float4*)(h + (size_t)r0 * IN_F);
        float4* hdst = (float4*)hs;
        #pragma unroll
        for (int t = 0; t < 4; ++t) hdst[tid + 256 * t] = hsrc[tid + 256 * t];
        __syncthreads();

        int w = tid >> 6, f = tid & 63;
        int br2 = w >> 1;
        int rbase = (w & 1) * 4;
        const float* W = br2 ? W2 : W1;
        const float4* hw4 = (const float4*)(hs + rbase * IN_F + br2 * HALF);
        float acc0 = 0.f, acc1 = 0.f, acc2 = 0.f, acc3 = 0.f;
        #pragma unroll 4
        for (int k4 = 0; k4 < HALF / 4; ++k4) {
            float4 h0 = hw4[k4];
            float4 h1 = hw4[k4 + IN_F / 4];
            float4 h2 = hw4[k4 + 2 * (IN_F / 4)];
            float4 h3 = hw4[k4 + 3 * (IN_F / 4)];
            int k = k4 << 2;
            float w0 = W[(k + 0) * FF + f];
            float w1 = W[(k + 1) * FF + f];
            float w2 = W[(k + 2) * FF + f];
            float w3 = W[(k + 3) * FF + f];
            acc0 += h0.x * w0 + h0.y * w1 + h0.z * w2 + h0.w * w3;
            acc1 += h1.x * w0 + h1.y * w1 + h1.z * w2 + h1.w * w3;
            acc2 += h2.x * w0 + h2.y * w1 + h2.z * w2 + h2.w * w3;
            acc3 += h3.x * w0 + h3.y * w1 + h3.z * w2 + h3.w * w3;
        }
        float* Wh = br2 ? Wh2 : Wh1;
        int rr = r0 + rbase;
        Wh[(size_t)(rr + 0) * FF + f] = acc0;
        Wh[(size_t)(rr + 1) * FF + f] = acc1;
        Wh[(size_t)(rr + 2) * FF + f] = acc2;
        Wh[(size_t)(rr + 3) * FF + f] = acc3;

        float a1 = a[f], a2 = a[64 + f];
        #pragma unroll
        for (int r = 0; r < 4; ++r) {
            float acc = (r == 0) ? acc0 : (r == 1) ? acc1 : (r == 2) ? acc2 : acc3;
            float v1 = acc * a1, v2 = acc * a2;
            #pragma unroll
            for (int off = 32; off; off >>= 1) {
                v1 += __shfl_down(v1, off, 64);
                v2 += __shfl_down(v2, off, 64);
            }
            if (f == 0) {
                if (br2 == 0) { s11[rr + r] = v1; s12[rr + r] = v2; }
                else          { s21[rr + r] = v1; s22[rr + r] = v2; }
            }
        }
    }
}

// ---------------- Kernel 2: fused attention, wave-local (1 wave = 1 row, both hops) ----------------
__global__ __launch_bounds__(256) void attn_kernel(const u64* __restrict__ packA,
                                                   const float* __restrict__ Wh1,
                                                   const float* __restrict__ Wh2,
                                                   const float* __restrict__ s11,
                                                   const float* __restrict__ s12,
                                                   const float* __restrict__ s21,
                                                   const float* __restrict__ s22,
                                                   float* __restrict__ hp) {
    __shared__ u16   nbr1s[4][CAP1];
    __shared__ u16   nbr2s[4][CAP2];
    __shared__ float evs[4][CAP2];

    int tid = threadIdx.x;
    int w = tid >> 6, lane = tid & 63;
    int i = blockIdx.x * 4 + w;

    u16*   nbr1 = nbr1s[w];
    u16*   nbr2 = nbr2s[w];
    float* ev   = evs[w];

    // ---- 1-hop list ----
    int t1 = build_idx16(packA[(size_t)i * 64 + lane], lane, CAP1, nbr1);
    int c1 = min(t1, CAP1);

    // ---- hop-1: softmax + gather (lane = column), 8-wide ILP ----
    float out1;
    if (c1 > 0) {
        int c1p = (c1 + 7) & ~7;
        if (lane < c1p - c1) { nbr1[c1 + lane] = 0; }
        float s11i = s11[i];
        float lm = -3.4e38f;
        for (int n = lane; n < c1; n += 64) {
            float e = lrelu(s11i + s12[nbr1[n]]);
            ev[n] = e;
            lm = fmaxf(lm, e);
        }
        float m = wave_fmax(lm);
        float ls = 0.f;
        for (int n = lane; n < c1; n += 64) {
            float p = __expf(ev[n] - m);
            ev[n] = p;
            ls += p;
        }
        float invZ = 1.f / wave_fsum(ls);
        if (lane < c1p - c1) { ev[c1 + lane] = 0.f; }
        float a0 = 0.f, a1 = 0.f, a2 = 0.f, a3 = 0.f;
        for (int n = 0; n < c1p; n += 8) {
            ushort4 nA = *(const ushort4*)&nbr1[n];
            ushort4 nB = *(const ushort4*)&nbr1[n + 4];
            float4  wA = *(const float4*)&ev[n];
            float4  wB = *(const float4*)&ev[n + 4];
            float q0 = Wh1[(int)nA.x * FF + lane];
            float q1 = Wh1[(int)nA.y * FF + lane];
            float q2 = Wh1[(int)nA.z * FF + lane];
            float q3 = Wh1[(int)nA.w * FF + lane];
            float q4 = Wh1[(int)nB.x * FF + lane];
            float q5 = Wh1[(int)nB.y * FF + lane];
            float q6 = Wh1[(int)nB.z * FF + lane];
            float q7 = Wh1[(int)nB.w * FF + lane];
            a0 += wA.x * q0 + wB.x * q4;
            a1 += wA.y * q1 + wB.y * q5;
            a2 += wA.z * q2 + wB.z * q6;
            a3 += wA.w * q3 + wB.w * q7;
        }
        out1 = ((a0 + a1) + (a2 + a3)) * invZ;
    } else {
        float a0 = 0.f, a1 = 0.f, a2 = 0.f, a3 = 0.f;
        for (int n = 0; n < NN; n += 4) {
            a0 += Wh1[(n + 0) * FF + lane];
            a1 += Wh1[(n + 1) * FF + lane];
            a2 += Wh1[(n + 2) * FF + lane];
            a3 += Wh1[(n + 3) * FF + lane];
        }
        out1 = ((a0 + a1) + (a2 + a3)) * (1.f / NN);
    }
    hp[(size_t)i * 128 + lane] = out1;

    // ---- 2-hop mask: OR of neighbor bit-rows, 4 independent accumulators ----
    u64 w0 = 0, w1 = 0, w2 = 0, w3 = 0;
    {
        int n = 0;
        for (; n + 4 <= c1; n += 4) {
            w0 |= packA[(int)nbr1[n + 0] * 64 + lane];
            w1 |= packA[(int)nbr1[n + 1] * 64 + lane];
            w2 |= packA[(int)nbr1[n + 2] * 64 + lane];
            w3 |= packA[(int)nbr1[n + 3] * 64 + lane];
        }
        for (; n < c1; ++n) w0 |= packA[(int)nbr1[n] * 64 + lane];
    }
    u64 word = (w0 | w1) | (w2 | w3);
    if (lane == (i >> 6)) word &= ~(1ull << (i & 63));   // zero adj2 diagonal

    int t2 = build_idx16(word, lane, CAP2, nbr2);
    int c2 = min(t2, CAP2);

    // ---- hop-2: softmax + gather, 8-wide ILP ----
    float out2;
    if (c2 > 0) {
        int c2p = (c2 + 7) & ~7;
        if (lane < c2p - c2) { nbr2[c2 + lane] = 0; }
        float s21i = s21[i];
        float lm = -3.4e38f;
        for (int n = lane; n < c2; n += 64) {
            float e = lrelu(s21i + s22[nbr2[n]]);
            ev[n] = e;
            lm = fmaxf(lm, e);
        }
        float m = wave_fmax(lm);
        float ls = 0.f;
        for (int n = lane; n < c2; n += 64) {
            float p = __expf(ev[n] - m);
            ev[n] = p;
            ls += p;
        }
        float invZ = 1.f / wave_fsum(ls);
        if (lane < c2p - c2) { ev[c2 + lane] = 0.f; }
        float a0 = 0.f, a1 = 0.f, a2 = 0.f, a3 = 0.f;
        for (int n = 0; n < c2p; n += 8) {
            ushort4 nA = *(const ushort4*)&nbr2[n];
            ushort4 nB = *(const ushort4*)&nbr2[n + 4];
            float4  wA = *(const float4*)&ev[n];
            float4  wB = *(const float4*)&ev[n + 4];
            float q0 = Wh2[(int)nA.x * FF + lane];
            float q1 = Wh2[(int)nA.y * FF + lane];
            float q2 = Wh2[(int)nA.z * FF + lane];
            float q3 = Wh2[(int)nA.w * FF + lane];
            float q4 = Wh2[(int)nB.x * FF + lane];
            float q5 = Wh2[(int)nB.y * FF + lane];
            float q6 = Wh2[(int)nB.z * FF + lane];
            float q7 = Wh2[(int)nB.w * FF + lane];
            a0 += wA.x * q0 + wB.x * q4;
            a1 += wA.y * q1 + wB.y * q5;
            a2 += wA.z * q2 + wB.z * q6;
            a3 += wA.w * q3 + wB.w * q7;
        }
        out2 = ((a0 + a1) + (a2 + a3)) * invZ;
    } else {
        float a0 = 0.f, a1 = 0.f, a2 = 0.f, a3 = 0.f;
        for (int n = 0; n < NN; n += 4) {
            a0 += Wh2[(n + 0) * FF + lane];
            a1 += Wh2[(n + 1) * FF + lane];
            a2 += Wh2[(n + 2) * FF + lane];
            a3 += Wh2[(n + 3) * FF + lane];
        }
        out2 = ((a0 + a1) + (a2 + a3)) * (1.f / NN);
    }
    hp[(size_t)i * 128 + 64 + lane] = out2;
}

// ---------------- Kernel 3: per-block column partials (128 blocks) ----------------
__global__ __launch_bounds__(256) void stats_kernel(const float* __restrict__ hp,
                                                    float* __restrict__ ps,
                                                    float* __restrict__ pq) {
    __shared__ float ls[128], lq[128];
    int tid = threadIdx.x;
    if (tid < 128) { ls[tid] = 0.f; lq[tid] = 0.f; }
    __syncthreads();
    float s0 = 0, s1 = 0, s2 = 0, s3 = 0, q0 = 0, q1 = 0, q2 = 0, q3 = 0;
    const float4* hp4 = (const float4*)hp;
    for (size_t idx = (size_t)blockIdx.x * 256 + tid; idx < (size_t)NN * 32;
         idx += (size_t)gridDim.x * 256) {
        float4 v = hp4[idx];
        s0 += v.x; q0 += v.x * v.x;
        s1 += v.y; q1 += v.y * v.y;
        s2 += v.z; q2 += v.z * v.z;
        s3 += v.w; q3 += v.w * v.w;
    }
    int cb = (tid & 31) << 2;
    atomicAdd(&ls[cb + 0], s0); atomicAdd(&lq[cb + 0], q0);
    atomicAdd(&ls[cb + 1], s1); atomicAdd(&lq[cb + 1], q1);
    atomicAdd(&ls[cb + 2], s2); atomicAdd(&lq[cb + 2], q2);
    atomicAdd(&ls[cb + 3], s3); atomicAdd(&lq[cb + 3], q3);
    __syncthreads();
    if (tid < 128) {
        ps[(size_t)blockIdx.x * 128 + tid] = ls[tid];
        pq[(size_t)blockIdx.x * 128 + tid] = lq[tid];
    }
}

// ---------------- Kernel 4: finalize (per-block re-reduce) + batchnorm + lrelu ----------------
__global__ __launch_bounds__(256) void normf_kernel(float* __restrict__ hp,
                                                    const float* __restrict__ ps,
                                                    const float* __restrict__ pq,
                                                    const float* __restrict__ gamma,
                                                    const float* __restrict__ beta) {
    __shared__ float csum[256];
    __shared__ float cmean[128], cginv[128];
    int tid = threadIdx.x;
    {
        const float* src = (tid < 128) ? ps : pq;
        int c = tid & 127;
        float s = 0.f;
        #pragma unroll 8
        for (int b = 0; b < 128; ++b) s += src[b * 128 + c];
        csum[tid] = s;
    }
    __syncthreads();
    if (tid < 128) {
        float mean = csum[tid] * (1.f / NN);
        float var = csum[128 + tid] * (1.f / NN) - mean * mean;
        cmean[tid] = mean;
        cginv[tid] = rsqrtf(var + EPSV) * gamma[tid];
    }
    __syncthreads();

    size_t idx = (size_t)blockIdx.x * 256 + tid;
    if (idx < (size_t)NN * 32) {
        int cb = (int)((idx << 2) & 127);
        float4 v = ((const float4*)hp)[idx];
        float r[4] = {v.x, v.y, v.z, v.w};
        #pragma unroll
        for (int t = 0; t < 4; ++t) {
            int c = cb + t;
            r[t] = lrelu((r[t] - cmean[c]) * cginv[c] + beta[c]);
        }
        ((float4*)hp)[idx] = make_float4(r[0], r[1], r[2], r[3]);
    }
}

extern "C" void kernel_launch(void* const* d_in, const int* in_sizes, int n_in,
                              void* d_out, int out_size, void* d_ws, size_t ws_size,
                              hipStream_t stream) {
    const float* h     = (const float*)d_in[0];
    const float* adj   = (const float*)d_in[1];
    const float* W1    = (const float*)d_in[2];
    const float* W2    = (const float*)d_in[3];
    const float* a     = (const float*)d_in[4];
    const float* gamma = (const float*)d_in[5];
    const float* beta  = (const float*)d_in[6];
    float* hp = (float*)d_out;   // [4096, 128]

    u64* packA  = (u64*)d_ws;                         // 2 MB (written as u16, read as u64)
    float* Wh1  = (float*)(packA + (size_t)NN * 64);  // 1 MB
    float* Wh2  = Wh1 + (size_t)NN * FF;              // 1 MB
    float* s11  = Wh2 + (size_t)NN * FF;
    float* s12  = s11 + NN;
    float* s21  = s12 + NN;
    float* s22  = s21 + NN;
    float* ps   = s22 + NN;                           // 128*128
    float* pq   = ps + 128 * 128;                     // 128*128

    packwh_kernel<<<NN + WHB, 256, 0, stream>>>(adj, (u16*)packA, h, W1, W2, a,
                                                Wh1, Wh2, s11, s12, s21, s22);
    attn_kernel<<<NN / 4, 256, 0, stream>>>(packA, Wh1, Wh2, s11, s12, s21, s22, hp);
    stats_kernel<<<128, 256, 0, stream>>>(hp, ps, pq);
    normf_kernel<<<(NN * 32 + 255) / 256, 256, 0, stream>>>(hp, ps, pq, gamma, beta);
}

// Round 9
// 163.236 us; speedup vs baseline: 1.1226x; 1.0127x over previous
//
#include <hip/hip_runtime.h>
#include <hip/hip_bf16.h>

#define NN 4096
#define IN_F 512
#define HALF 256
#define FF 64
#define ALPHA 0.2f
#define EPSV 1e-5f
#define CAP1 128
#define CAP2 1024

typedef unsigned long long u64;
typedef unsigned int u32;
typedef unsigned short u16;
typedef unsigned char u8;

__device__ __forceinline__ float lrelu(float x){ return x > 0.f ? x : ALPHA * x; }

__device__ __forceinline__ float wave_fmax(float v){
    #pragma unroll
    for (int off = 32; off; off >>= 1) v = fmaxf(v, __shfl_xor(v, off, 64));
    return v;
}
__device__ __forceinline__ float wave_fsum(float v){
    #pragma unroll
    for (int off = 32; off; off >>= 1) v += __shfl_xor(v, off, 64);
    return v;
}

// Wave-wide compaction of set bits (one u64 word per lane) into a u16 index list.
__device__ __forceinline__ int build_idx16(u64 bits, int lane, int cap, u16* __restrict__ nbr){
    int pc = __popcll(bits);
    int scan = pc;
    #pragma unroll
    for (int off = 1; off < 64; off <<= 1) {
        int v = __shfl_up(scan, off, 64);
        if (lane >= off) scan += v;
    }
    int total = __shfl(scan, 63, 64);
    int pos = scan - pc;
    while (bits) {
        int b = __builtin_ctzll(bits);
        bits &= bits - 1;
        if (pos < cap) nbr[pos] = (u16)((lane << 6) | b);
        ++pos;
    }
    return total;
}

// ---------------- Kernel 1: bit-pack adjacency — coalesced, no cross-lane ops ----------------
// Phase A: 4 coalesced float4 loads/thread -> 4 nibbles -> LDS byte array (1024 B).
// Phase B: each thread reads one LDS u32 (4 nibbles) -> one u16 word of the row mask.
// pack16 little-endian u16[256]/row is bit-identical to the u64[64] view consumers read.
__global__ __launch_bounds__(256) void pack_kernel(const float* __restrict__ adj,
                                                   u16* __restrict__ pack16) {
    __shared__ u8 nib[1024];
    int i = blockIdx.x;
    int tid = threadIdx.x;
    const float4* row = (const float4*)(adj + (size_t)i * NN);
    float4 v0 = row[tid];
    float4 v1 = row[256 + tid];
    float4 v2 = row[512 + tid];
    float4 v3 = row[768 + tid];
    nib[tid]       = (u8)((v0.x > 0.f) | ((u32)(v0.y > 0.f) << 1) | ((u32)(v0.z > 0.f) << 2) | ((u32)(v0.w > 0.f) << 3));
    nib[256 + tid] = (u8)((v1.x > 0.f) | ((u32)(v1.y > 0.f) << 1) | ((u32)(v1.z > 0.f) << 2) | ((u32)(v1.w > 0.f) << 3));
    nib[512 + tid] = (u8)((v2.x > 0.f) | ((u32)(v2.y > 0.f) << 1) | ((u32)(v2.z > 0.f) << 2) | ((u32)(v2.w > 0.f) << 3));
    nib[768 + tid] = (u8)((v3.x > 0.f) | ((u32)(v3.y > 0.f) << 1) | ((u32)(v3.z > 0.f) << 2) | ((u32)(v3.w > 0.f) << 3));
    __syncthreads();
    u32 x = ((const u32*)nib)[tid];
    u16 wd = (u16)((x & 0xFu) | ((x >> 4) & 0xF0u) | ((x >> 8) & 0xF00u) | ((x >> 12) & 0xF000u));
    pack16[(size_t)i * 256 + tid] = wd;
}

// ---------------- Kernel 2: Wh GEMV, 8 rows/block, float4 LDS reads ----------------
__global__ __launch_bounds__(256) void wh_kernel(const float* __restrict__ h,
                                                 const float* __restrict__ W1,
                                                 const float* __restrict__ W2,
                                                 const float* __restrict__ a,
                                                 float* __restrict__ Wh1,
                                                 float* __restrict__ Wh2,
                                                 float* __restrict__ s11,
                                                 float* __restrict__ s12,
                                                 float* __restrict__ s21,
                                                 float* __restrict__ s22) {
    __shared__ float hs[8 * IN_F];
    int tid = threadIdx.x;
    int r0 = blockIdx.x * 8;
    const float4* hsrc = (const float4*)(h + (size_t)r0 * IN_F);
    float4* hdst = (float4*)hs;
    #pragma unroll
    for (int t = 0; t < 4; ++t) hdst[tid + 256 * t] = hsrc[tid + 256 * t];
    __syncthreads();

    int w = tid >> 6, f = tid & 63;
    int br2 = w >> 1;
    int rbase = (w & 1) * 4;
    const float* W = br2 ? W2 : W1;
    const float4* hw4 = (const float4*)(hs + rbase * IN_F + br2 * HALF);
    float acc0 = 0.f, acc1 = 0.f, acc2 = 0.f, acc3 = 0.f;
    #pragma unroll 4
    for (int k4 = 0; k4 < HALF / 4; ++k4) {
        float4 h0 = hw4[k4];
        float4 h1 = hw4[k4 + IN_F / 4];
        float4 h2 = hw4[k4 + 2 * (IN_F / 4)];
        float4 h3 = hw4[k4 + 3 * (IN_F / 4)];
        int k = k4 << 2;
        float w0 = W[(k + 0) * FF + f];
        float w1 = W[(k + 1) * FF + f];
        float w2 = W[(k + 2) * FF + f];
        float w3 = W[(k + 3) * FF + f];
        acc0 += h0.x * w0 + h0.y * w1 + h0.z * w2 + h0.w * w3;
        acc1 += h1.x * w0 + h1.y * w1 + h1.z * w2 + h1.w * w3;
        acc2 += h2.x * w0 + h2.y * w1 + h2.z * w2 + h2.w * w3;
        acc3 += h3.x * w0 + h3.y * w1 + h3.z * w2 + h3.w * w3;
    }
    float* Wh = br2 ? Wh2 : Wh1;
    int rr = r0 + rbase;
    Wh[(size_t)(rr + 0) * FF + f] = acc0;
    Wh[(size_t)(rr + 1) * FF + f] = acc1;
    Wh[(size_t)(rr + 2) * FF + f] = acc2;
    Wh[(size_t)(rr + 3) * FF + f] = acc3;

    float a1 = a[f], a2 = a[64 + f];
    #pragma unroll
    for (int r = 0; r < 4; ++r) {
        float acc = (r == 0) ? acc0 : (r == 1) ? acc1 : (r == 2) ? acc2 : acc3;
        float v1 = acc * a1, v2 = acc * a2;
        #pragma unroll
        for (int off = 32; off; off >>= 1) {
            v1 += __shfl_down(v1, off, 64);
            v2 += __shfl_down(v2, off, 64);
        }
        if (f == 0) {
            if (br2 == 0) { s11[rr + r] = v1; s12[rr + r] = v2; }
            else          { s21[rr + r] = v1; s22[rr + r] = v2; }
        }
    }
}

// ---------------- Kernel 3: fused attention, wave-local (1 wave = 1 row, both hops) ----------------
__global__ __launch_bounds__(256) void attn_kernel(const u64* __restrict__ packA,
                                                   const float* __restrict__ Wh1,
                                                   const float* __restrict__ Wh2,
                                                   const float* __restrict__ s11,
                                                   const float* __restrict__ s12,
                                                   const float* __restrict__ s21,
                                                   const float* __restrict__ s22,
                                                   float* __restrict__ hp) {
    __shared__ u16   nbr1s[4][CAP1];
    __shared__ u16   nbr2s[4][CAP2];
    __shared__ float evs[4][CAP2];

    int tid = threadIdx.x;
    int w = tid >> 6, lane = tid & 63;
    int i = blockIdx.x * 4 + w;

    u16*   nbr1 = nbr1s[w];
    u16*   nbr2 = nbr2s[w];
    float* ev   = evs[w];

    // ---- 1-hop list ----
    int t1 = build_idx16(packA[(size_t)i * 64 + lane], lane, CAP1, nbr1);
    int c1 = min(t1, CAP1);

    // ---- hop-1: softmax + gather (lane = column), 8-wide ILP ----
    float out1;
    if (c1 > 0) {
        int c1p = (c1 + 7) & ~7;
        if (lane < c1p - c1) { nbr1[c1 + lane] = 0; }
        float s11i = s11[i];
        float lm = -3.4e38f;
        for (int n = lane; n < c1; n += 64) {
            float e = lrelu(s11i + s12[nbr1[n]]);
            ev[n] = e;
            lm = fmaxf(lm, e);
        }
        float m = wave_fmax(lm);
        float ls = 0.f;
        for (int n = lane; n < c1; n += 64) {
            float p = __expf(ev[n] - m);
            ev[n] = p;
            ls += p;
        }
        float invZ = 1.f / wave_fsum(ls);
        if (lane < c1p - c1) { ev[c1 + lane] = 0.f; }
        float a0 = 0.f, a1 = 0.f, a2 = 0.f, a3 = 0.f;
        for (int n = 0; n < c1p; n += 8) {
            ushort4 nA = *(const ushort4*)&nbr1[n];
            ushort4 nB = *(const ushort4*)&nbr1[n + 4];
            float4  wA = *(const float4*)&ev[n];
            float4  wB = *(const float4*)&ev[n + 4];
            float q0 = Wh1[(int)nA.x * FF + lane];
            float q1 = Wh1[(int)nA.y * FF + lane];
            float q2 = Wh1[(int)nA.z * FF + lane];
            float q3 = Wh1[(int)nA.w * FF + lane];
            float q4 = Wh1[(int)nB.x * FF + lane];
            float q5 = Wh1[(int)nB.y * FF + lane];
            float q6 = Wh1[(int)nB.z * FF + lane];
            float q7 = Wh1[(int)nB.w * FF + lane];
            a0 += wA.x * q0 + wB.x * q4;
            a1 += wA.y * q1 + wB.y * q5;
            a2 += wA.z * q2 + wB.z * q6;
            a3 += wA.w * q3 + wB.w * q7;
        }
        out1 = ((a0 + a1) + (a2 + a3)) * invZ;
    } else {
        float a0 = 0.f, a1 = 0.f, a2 = 0.f, a3 = 0.f;
        for (int n = 0; n < NN; n += 4) {
            a0 += Wh1[(n + 0) * FF + lane];
            a1 += Wh1[(n + 1) * FF + lane];
            a2 += Wh1[(n + 2) * FF + lane];
            a3 += Wh1[(n + 3) * FF + lane];
        }
        out1 = ((a0 + a1) + (a2 + a3)) * (1.f / NN);
    }
    hp[(size_t)i * 128 + lane] = out1;

    // ---- 2-hop mask: OR of neighbor bit-rows, 4 independent accumulators ----
    u64 w0 = 0, w1 = 0, w2 = 0, w3 = 0;
    {
        int n = 0;
        for (; n + 4 <= c1; n += 4) {
            w0 |= packA[(int)nbr1[n + 0] * 64 + lane];
            w1 |= packA[(int)nbr1[n + 1] * 64 + lane];
            w2 |= packA[(int)nbr1[n + 2] * 64 + lane];
            w3 |= packA[(int)nbr1[n + 3] * 64 + lane];
        }
        for (; n < c1; ++n) w0 |= packA[(int)nbr1[n] * 64 + lane];
    }
    u64 word = (w0 | w1) | (w2 | w3);
    if (lane == (i >> 6)) word &= ~(1ull << (i & 63));   // zero adj2 diagonal

    int t2 = build_idx16(word, lane, CAP2, nbr2);
    int c2 = min(t2, CAP2);

    // ---- hop-2: softmax + gather, 8-wide ILP ----
    float out2;
    if (c2 > 0) {
        int c2p = (c2 + 7) & ~7;
        if (lane < c2p - c2) { nbr2[c2 + lane] = 0; }
        float s21i = s21[i];
        float lm = -3.4e38f;
        for (int n = lane; n < c2; n += 64) {
            float e = lrelu(s21i + s22[nbr2[n]]);
            ev[n] = e;
            lm = fmaxf(lm, e);
        }
        float m = wave_fmax(lm);
        float ls = 0.f;
        for (int n = lane; n < c2; n += 64) {
            float p = __expf(ev[n] - m);
            ev[n] = p;
            ls += p;
        }
        float invZ = 1.f / wave_fsum(ls);
        if (lane < c2p - c2) { ev[c2 + lane] = 0.f; }
        float a0 = 0.f, a1 = 0.f, a2 = 0.f, a3 = 0.f;
        for (int n = 0; n < c2p; n += 8) {
            ushort4 nA = *(const ushort4*)&nbr2[n];
            ushort4 nB = *(const ushort4*)&nbr2[n + 4];
            float4  wA = *(const float4*)&ev[n];
            float4  wB = *(const float4*)&ev[n + 4];
            float q0 = Wh2[(int)nA.x * FF + lane];
            float q1 = Wh2[(int)nA.y * FF + lane];
            float q2 = Wh2[(int)nA.z * FF + lane];
            float q3 = Wh2[(int)nA.w * FF + lane];
            float q4 = Wh2[(int)nB.x * FF + lane];
            float q5 = Wh2[(int)nB.y * FF + lane];
            float q6 = Wh2[(int)nB.z * FF + lane];
            float q7 = Wh2[(int)nB.w * FF + lane];
            a0 += wA.x * q0 + wB.x * q4;
            a1 += wA.y * q1 + wB.y * q5;
            a2 += wA.z * q2 + wB.z * q6;
            a3 += wA.w * q3 + wB.w * q7;
        }
        out2 = ((a0 + a1) + (a2 + a3)) * invZ;
    } else {
        float a0 = 0.f, a1 = 0.f, a2 = 0.f, a3 = 0.f;
        for (int n = 0; n < NN; n += 4) {
            a0 += Wh2[(n + 0) * FF + lane];
            a1 += Wh2[(n + 1) * FF + lane];
            a2 += Wh2[(n + 2) * FF + lane];
            a3 += Wh2[(n + 3) * FF + lane];
        }
        out2 = ((a0 + a1) + (a2 + a3)) * (1.f / NN);
    }
    hp[(size_t)i * 128 + 64 + lane] = out2;
}

// ---------------- Kernel 4: per-block column partials (128 blocks) ----------------
__global__ __launch_bounds__(256) void stats_kernel(const float* __restrict__ hp,
                                                    float* __restrict__ ps,
                                                    float* __restrict__ pq) {
    __shared__ float ls[128], lq[128];
    int tid = threadIdx.x;
    if (tid < 128) { ls[tid] = 0.f; lq[tid] = 0.f; }
    __syncthreads();
    float s0 = 0, s1 = 0, s2 = 0, s3 = 0, q0 = 0, q1 = 0, q2 = 0, q3 = 0;
    const float4* hp4 = (const float4*)hp;
    for (size_t idx = (size_t)blockIdx.x * 256 + tid; idx < (size_t)NN * 32;
         idx += (size_t)gridDim.x * 256) {
        float4 v = hp4[idx];
        s0 += v.x; q0 += v.x * v.x;
        s1 += v.y; q1 += v.y * v.y;
        s2 += v.z; q2 += v.z * v.z;
        s3 += v.w; q3 += v.w * v.w;
    }
    int cb = (tid & 31) << 2;
    atomicAdd(&ls[cb + 0], s0); atomicAdd(&lq[cb + 0], q0);
    atomicAdd(&ls[cb + 1], s1); atomicAdd(&lq[cb + 1], q1);
    atomicAdd(&ls[cb + 2], s2); atomicAdd(&lq[cb + 2], q2);
    atomicAdd(&ls[cb + 3], s3); atomicAdd(&lq[cb + 3], q3);
    __syncthreads();
    if (tid < 128) {
        ps[(size_t)blockIdx.x * 128 + tid] = ls[tid];
        pq[(size_t)blockIdx.x * 128 + tid] = lq[tid];
    }
}

// ---------------- Kernel 5: finalize (per-block re-reduce) + batchnorm + lrelu ----------------
__global__ __launch_bounds__(256) void normf_kernel(float* __restrict__ hp,
                                                    const float* __restrict__ ps,
                                                    const float* __restrict__ pq,
                                                    const float* __restrict__ gamma,
                                                    const float* __restrict__ beta) {
    __shared__ float csum[256];
    __shared__ float cmean[128], cginv[128];
    int tid = threadIdx.x;
    {
        const float* src = (tid < 128) ? ps : pq;
        int c = tid & 127;
        float s = 0.f;
        #pragma unroll 8
        for (int b = 0; b < 128; ++b) s += src[b * 128 + c];
        csum[tid] = s;
    }
    __syncthreads();
    if (tid < 128) {
        float mean = csum[tid] * (1.f / NN);
        float var = csum[128 + tid] * (1.f / NN) - mean * mean;
        cmean[tid] = mean;
        cginv[tid] = rsqrtf(var + EPSV) * gamma[tid];
    }
    __syncthreads();

    size_t idx = (size_t)blockIdx.x * 256 + tid;
    if (idx < (size_t)NN * 32) {
        int cb = (int)((idx << 2) & 127);
        float4 v = ((const float4*)hp)[idx];
        float r[4] = {v.x, v.y, v.z, v.w};
        #pragma unroll
        for (int t = 0; t < 4; ++t) {
            int c = cb + t;
            r[t] = lrelu((r[t] - cmean[c]) * cginv[c] + beta[c]);
        }
        ((float4*)hp)[idx] = make_float4(r[0], r[1], r[2], r[3]);
    }
}

extern "C" void kernel_launch(void* const* d_in, const int* in_sizes, int n_in,
                              void* d_out, int out_size, void* d_ws, size_t ws_size,
                              hipStream_t stream) {
    const float* h     = (const float*)d_in[0];
    const float* adj   = (const float*)d_in[1];
    const float* W1    = (const float*)d_in[2];
    const float* W2    = (const float*)d_in[3];
    const float* a     = (const float*)d_in[4];
    const float* gamma = (const float*)d_in[5];
    const float* beta  = (const float*)d_in[6];
    float* hp = (float*)d_out;   // [4096, 128]

    u64* packA  = (u64*)d_ws;                         // 2 MB (written as u16, read as u64)
    float* Wh1  = (float*)(packA + (size_t)NN * 64);  // 1 MB
    float* Wh2  = Wh1 + (size_t)NN * FF;              // 1 MB
    float* s11  = Wh2 + (size_t)NN * FF;
    float* s12  = s11 + NN;
    float* s21  = s12 + NN;
    float* s22  = s21 + NN;
    float* ps   = s22 + NN;                           // 128*128
    float* pq   = ps + 128 * 128;                     // 128*128

    pack_kernel<<<NN, 256, 0, stream>>>(adj, (u16*)packA);
    wh_kernel<<<NN / 8, 256, 0, stream>>>(h, W1, W2, a, Wh1, Wh2, s11, s12, s21, s22);
    attn_kernel<<<NN / 4, 256, 0, stream>>>(packA, Wh1, Wh2, s11, s12, s21, s22, hp);
    stats_kernel<<<128, 256, 0, stream>>>(hp, ps, pq);
    normf_kernel<<<(NN * 32 + 255) / 256, 256, 0, stream>>>(hp, ps, pq, gamma, beta);
}